// Round 7
// baseline (83.686 us; speedup 1.0000x reference)
//
#include <hip/hip_runtime.h>
#include <math.h>

#define BATCH 32
#define CH    128
#define HW    4096   // 64*64

typedef short short8 __attribute__((ext_vector_type(8)));   // 8 bf16 (4 VGPRs)
typedef float f32x4  __attribute__((ext_vector_type(4)));   // MFMA accumulator

#define SWZ(n) ((((n) >> 2) & 7) << 3)   // XOR swizzle of k-index by row

__device__ __forceinline__ unsigned short f2bf(float f) {   // RNE float->bf16
    unsigned int u = __float_as_uint(f);
    u = (u + 0x7FFF + ((u >> 16) & 1)) >> 16;
    return (unsigned short)u;
}
__device__ __forceinline__ float bf2f(unsigned short s) {
    return __uint_as_float(((unsigned int)s) << 16);
}
__device__ __forceinline__ float comp(const float4& v, int r) {  // static r after unroll
    return (r == 0) ? v.x : (r == 1) ? v.y : (r == 2) ? v.z : v.w;
}

// ---------------------------------------------------------------------------
// Kernel 1: pooled[b*C+c] = mean over HW of condition[b,c,:,:]
// ---------------------------------------------------------------------------
__global__ __launch_bounds__(256) void pool_kernel(const float* __restrict__ cond,
                                                   float* __restrict__ pooled) {
    int bc = blockIdx.x;
    const float4* base = (const float4*)(cond + (size_t)bc * HW);
    int tid = threadIdx.x;
    float s = 0.f;
#pragma unroll
    for (int k = 0; k < 4; ++k) {
        float4 v = base[tid + k * 256];
        s += v.x + v.y + v.z + v.w;
    }
    for (int off = 32; off; off >>= 1) s += __shfl_down(s, off, 64);
    __shared__ float red[4];
    if ((tid & 63) == 0) red[tid >> 6] = s;
    __syncthreads();
    if (tid == 0) pooled[bc] = (red[0] + red[1] + red[2] + red[3]) * (1.0f / HW);
}

// ---------------------------------------------------------------------------
// Kernel 2: wmat[b][o][i] = dot(pooled[b], w_lin[o*C+i]) + b_lin + (o==i)
// fp32 copy for logdet diagonal + bf16 copy for both MFMA consumers.
// ---------------------------------------------------------------------------
__global__ __launch_bounds__(256) void wmat_kernel(const float* __restrict__ pooled,
                                                   const float* __restrict__ w_lin,
                                                   const float* __restrict__ b_lin,
                                                   float* __restrict__ wmat,
                                                   unsigned short* __restrict__ wmatb) {
    __shared__ float4 pl[BATCH * CH / 4];   // pooled staged: pl[b*32 + k4]
    int tid = threadIdx.x;
    const float4* p4 = (const float4*)pooled;
    for (int idx = tid; idx < BATCH * CH / 4; idx += 256) pl[idx] = p4[idx];
    __syncthreads();

    int n = blockIdx.x * 256 + tid;
    const float4* row = (const float4*)(w_lin + (size_t)n * CH);
    float bl = b_lin[n];
    float acc[BATCH];
#pragma unroll
    for (int b = 0; b < BATCH; ++b) acc[b] = bl;

    for (int k4 = 0; k4 < CH / 4; ++k4) {
        float4 wv = row[k4];
#pragma unroll
        for (int b = 0; b < BATCH; ++b) {
            float4 pv = pl[b * 32 + k4];
            acc[b] += pv.x * wv.x + pv.y * wv.y + pv.z * wv.z + pv.w * wv.w;
        }
    }
    int o = n >> 7, i = n & 127;
    float diag = (o == i) ? 1.0f : 0.0f;
#pragma unroll
    for (int b = 0; b < BATCH; ++b) {
        float v = acc[b] + diag;
        wmat [(size_t)b * (CH * CH) + n] = v;
        wmatb[(size_t)b * (CH * CH) + n] = f2bf(v);
    }
}

// ---------------------------------------------------------------------------
// Kernel 3: MFMA conv. grid = 1024 blocks (32 b x 32 tiles of 128 pix).
// __launch_bounds__(256,4): VGPR<=128 -> 4 waves/SIMD -> ~4 blocks/CU
// co-resident (LDS 34.8KB allows 4). Swapped-operand MFMA gives D[pix][och]
// so each f32x4 acc = 4 consecutive pixels -> float4 stores (16 vs 64 instrs).
// ---------------------------------------------------------------------------
__global__ __launch_bounds__(256, 4) void conv_kernel(const float* __restrict__ inp,
                                                      const unsigned short* __restrict__ wmatb,
                                                      float* __restrict__ out) {
    __shared__ __align__(16) short X[CH * 136];   // bf16 [pix][k^swz], 34816 B
    int tid  = threadIdx.x;
    int lane = tid & 63;
    int ln   = lane & 15;                // row/col within 16
    int lg   = lane >> 4;                // k-group 0..3
    int och0 = (tid >> 6) * 32;          // wave's och base

    int b    = blockIdx.x >> 5;          // 0..31
    int tile = blockIdx.x & 31;          // 0..31
    int pix0 = tile * 128;

    int q  = tid & 31;                   // pixel-quad: pix = 4q..4q+3
    int ks = tid >> 5;                   // 0..7
    const float* sb = inp + (size_t)b * CH * HW + pix0 + 4 * q;

    // ---- issue all 16 X loads in two 8-reg batches (keeps VGPR under cap)
    float4 s0[8], s1[8];
#pragma unroll
    for (int m = 0; m < 2; ++m)
#pragma unroll
        for (int r = 0; r < 4; ++r)
            s0[m * 4 + r] = *(const float4*)(sb + (size_t)(m * 32 + ks * 4 + r) * HW);
#pragma unroll
    for (int m = 0; m < 2; ++m)
#pragma unroll
        for (int r = 0; r < 4; ++r)
            s1[m * 4 + r] = *(const float4*)(sb + (size_t)((m + 2) * 32 + ks * 4 + r) * HW);

    // ---- A fragments (W bf16 rows, L2-hot) while X loads are in flight
    const unsigned short* wb = wmatb + (size_t)b * CH * CH;
    short8 afr[2][4];
#pragma unroll
    for (int mt = 0; mt < 2; ++mt)
#pragma unroll
        for (int g = 0; g < 4; ++g)
            afr[mt][g] = *(const short8*)&wb[(size_t)(och0 + mt * 16 + ln) * CH + g * 32 + lg * 8];

    // ---- convert -> bf16 LDS [pix][k^swz] (in-thread 4x4 transpose)
#pragma unroll
    for (int m = 0; m < 2; ++m) {
        int k0 = m * 32 + ks * 4;
#pragma unroll
        for (int r = 0; r < 4; ++r) {
            int pix = 4 * q + r;
            ushort4 v;
            v.x = f2bf(comp(s0[m * 4 + 0], r));
            v.y = f2bf(comp(s0[m * 4 + 1], r));
            v.z = f2bf(comp(s0[m * 4 + 2], r));
            v.w = f2bf(comp(s0[m * 4 + 3], r));
            *(ushort4*)&X[pix * 136 + (k0 ^ SWZ(pix))] = v;
        }
    }
#pragma unroll
    for (int m = 0; m < 2; ++m) {
        int k0 = (m + 2) * 32 + ks * 4;
#pragma unroll
        for (int r = 0; r < 4; ++r) {
            int pix = 4 * q + r;
            ushort4 v;
            v.x = f2bf(comp(s1[m * 4 + 0], r));
            v.y = f2bf(comp(s1[m * 4 + 1], r));
            v.z = f2bf(comp(s1[m * 4 + 2], r));
            v.w = f2bf(comp(s1[m * 4 + 3], r));
            *(ushort4*)&X[pix * 136 + (k0 ^ SWZ(pix))] = v;
        }
    }
    __syncthreads();

    // ---- MFMA: acc[mt][nt] = D[pix-tile nt][och-tile mt], A=X-frag B=W-frag
    f32x4 acc[2][8];
#pragma unroll
    for (int mt = 0; mt < 2; ++mt)
#pragma unroll
        for (int nt = 0; nt < 8; ++nt) acc[mt][nt] = (f32x4){0.f, 0.f, 0.f, 0.f};

#pragma unroll
    for (int g = 0; g < 4; ++g) {
#pragma unroll
        for (int nt = 0; nt < 8; ++nt) {
            int pix = nt * 16 + ln;
            short8 bfr = *(const short8*)&X[pix * 136 + ((g * 32 + lg * 8) ^ SWZ(pix))];
            acc[0][nt] = __builtin_amdgcn_mfma_f32_16x16x32_bf16(bfr, afr[0][g], acc[0][nt], 0, 0, 0);
            acc[1][nt] = __builtin_amdgcn_mfma_f32_16x16x32_bf16(bfr, afr[1][g], acc[1][nt], 0, 0, 0);
        }
    }

    // ---- store: D col=ln(och), row=lg*4+reg(pix) -> float4 over pix
    float* ob = out + (size_t)b * CH * HW + pix0;
#pragma unroll
    for (int mt = 0; mt < 2; ++mt) {
        int och = och0 + mt * 16 + ln;
#pragma unroll
        for (int nt = 0; nt < 8; ++nt) {
            int px = nt * 16 + lg * 4;
            float4 v = make_float4(acc[mt][nt][0], acc[mt][nt][1],
                                   acc[mt][nt][2], acc[mt][nt][3]);
            *(float4*)(ob + (size_t)och * HW + px) = v;
        }
    }
}

// ---------------------------------------------------------------------------
// Kernel 4: per-sample log|det W| via MFMA series (validated in round 4/5).
//   Ê = bf16(W) with zero diagonal; exact diag d_r = W_rr - 1 in fp32:
//     ld = sum_r[log(1+d_r) + D_rr*d_r - D_rr/2]
//        + sum_rc D[r][c]*Ê[c][r]/3 - sum_rc D[r][c]*D[c][r]/4,  D = Ê²
// ---------------------------------------------------------------------------
__global__ __launch_bounds__(256) void logdet_kernel(const float* __restrict__ wmat,
                                                     const unsigned short* __restrict__ wmatb,
                                                     float* __restrict__ partial) {
    __shared__ __align__(16) short X[CH * 136];
    int tid  = threadIdx.x;
    int lane = tid & 63;
    int ln   = lane & 15;
    int lg   = lane >> 4;
    int och0 = (tid >> 6) * 32;

    int b = blockIdx.x;
    const float*          Wb = wmat  + (size_t)b * CH * CH;
    const unsigned short* wb = wmatb + (size_t)b * CH * CH;

    // ---- stage ÊT[n][k^swz] = Ê[k][n], diag zeroed (transpose of W rows)
    {
        int q  = tid & 31;           // col-quad: n = 4q..4q+3
        int ks = tid >> 5;           // 0..7
        const float* sb = Wb + 4 * q;
#pragma unroll
        for (int m = 0; m < 4; ++m) {
            int k0 = m * 32 + ks * 4;
            float4 r0 = *(const float4*)(sb + (size_t)(k0 + 0) * CH);
            float4 r1 = *(const float4*)(sb + (size_t)(k0 + 1) * CH);
            float4 r2 = *(const float4*)(sb + (size_t)(k0 + 2) * CH);
            float4 r3 = *(const float4*)(sb + (size_t)(k0 + 3) * CH);
#pragma unroll
            for (int r = 0; r < 4; ++r) {
                int n = 4 * q + r;
                float a0 = comp(r0, r), a1 = comp(r1, r);
                float a2 = comp(r2, r), a3 = comp(r3, r);
                if (k0 + 0 == n) a0 = 0.f;
                if (k0 + 1 == n) a1 = 0.f;
                if (k0 + 2 == n) a2 = 0.f;
                if (k0 + 3 == n) a3 = 0.f;
                ushort4 v;
                v.x = f2bf(a0); v.y = f2bf(a1); v.z = f2bf(a2); v.w = f2bf(a3);
                *(ushort4*)&X[n * 136 + (k0 ^ SWZ(n))] = v;
            }
        }
    }

    // ---- A fragments: Ê rows from wmatb, diag slot zeroed
    short8 afr[2][4];
#pragma unroll
    for (int mt = 0; mt < 2; ++mt) {
        int row = och0 + mt * 16 + ln;
#pragma unroll
        for (int g = 0; g < 4; ++g) {
            short8 v = *(const short8*)&wb[(size_t)row * CH + g * 32 + lg * 8];
#pragma unroll
            for (int j = 0; j < 8; ++j)
                if (g * 32 + lg * 8 + j == row) v[j] = 0;
            afr[mt][g] = v;
        }
    }
    __syncthreads();

    // ---- D = Ê² via MFMA
    f32x4 acc[2][8];
#pragma unroll
    for (int mt = 0; mt < 2; ++mt)
#pragma unroll
        for (int nt = 0; nt < 8; ++nt) acc[mt][nt] = (f32x4){0.f, 0.f, 0.f, 0.f};
#pragma unroll
    for (int g = 0; g < 4; ++g) {
#pragma unroll
        for (int nt = 0; nt < 8; ++nt) {
            int n = nt * 16 + ln;
            short8 bfr = *(const short8*)&X[n * 136 + ((g * 32 + lg * 8) ^ SWZ(n))];
            acc[0][nt] = __builtin_amdgcn_mfma_f32_16x16x32_bf16(afr[0][g], bfr, acc[0][nt], 0, 0, 0);
            acc[1][nt] = __builtin_amdgcn_mfma_f32_16x16x32_bf16(afr[1][g], bfr, acc[1][nt], 0, 0, 0);
        }
    }

    // ---- traces: t3 (ÊT still in LDS) + diagonal terms
    float ld = 0.f;
#pragma unroll
    for (int mt = 0; mt < 2; ++mt) {
#pragma unroll
        for (int nt = 0; nt < 8; ++nt) {
#pragma unroll
            for (int reg = 0; reg < 4; ++reg) {
                int row = och0 + mt * 16 + lg * 4 + reg;
                int col = nt * 16 + ln;
                float v = acc[mt][nt][reg];
                float eT = bf2f((unsigned short)X[row * 136 + (col ^ SWZ(row))]); // Ê[col][row]
                ld += v * eT * (1.f / 3.f);
                if (row == col) {
                    float d = Wb[(size_t)row * CH + row] - 1.0f;
                    ld += logf(fabsf(1.f + d)) + v * d - 0.5f * v;
                }
            }
        }
    }
    __syncthreads();   // all ÊT reads done -> reuse LDS for D

    // ---- write D (bf16) for the transpose needed by tr(Ê⁴)
#pragma unroll
    for (int mt = 0; mt < 2; ++mt)
#pragma unroll
        for (int nt = 0; nt < 8; ++nt)
#pragma unroll
            for (int reg = 0; reg < 4; ++reg) {
                int row = och0 + mt * 16 + lg * 4 + reg;
                int col = nt * 16 + ln;
                X[row * 136 + (col ^ SWZ(row))] = (short)f2bf(acc[mt][nt][reg]);
            }
    __syncthreads();

    // ---- t4 = sum D[r][c]*D[c][r]
#pragma unroll
    for (int mt = 0; mt < 2; ++mt)
#pragma unroll
        for (int nt = 0; nt < 8; ++nt)
#pragma unroll
            for (int reg = 0; reg < 4; ++reg) {
                int row = och0 + mt * 16 + lg * 4 + reg;
                int col = nt * 16 + ln;
                float dT = bf2f((unsigned short)X[col * 136 + (row ^ SWZ(col))]); // D[col][row]
                ld -= acc[mt][nt][reg] * dT * 0.25f;
            }

    for (int off = 32; off; off >>= 1) ld += __shfl_down(ld, off, 64);
    __syncthreads();   // all D reads done -> reuse LDS head for reduction
    float* red = (float*)X;
    if (lane == 0) red[tid >> 6] = ld;
    __syncthreads();
    if (tid == 0) partial[b] = red[0] + red[1] + red[2] + red[3];
}

// ---------------------------------------------------------------------------
// Kernel 5: log_det = HW * mean_b(partial[b]) = sum * 128
// ---------------------------------------------------------------------------
__global__ void finalize_kernel(const float* __restrict__ partial,
                                float* __restrict__ out_scalar) {
    int tid = threadIdx.x;
    float v = (tid < BATCH) ? partial[tid] : 0.f;
    for (int off = 32; off; off >>= 1) v += __shfl_down(v, off, 64);
    if (tid == 0) out_scalar[0] = v * 128.0f;
}

// ---------------------------------------------------------------------------
extern "C" void kernel_launch(void* const* d_in, const int* in_sizes, int n_in,
                              void* d_out, int out_size, void* d_ws, size_t ws_size,
                              hipStream_t stream) {
    const float* inp   = (const float*)d_in[0];
    const float* cond  = (const float*)d_in[1];
    const float* w_lin = (const float*)d_in[2];
    const float* b_lin = (const float*)d_in[3];
    float* out = (float*)d_out;

    float* pooled          = (float*)d_ws;                    // 4096 floats
    float* wmat            = pooled + BATCH * CH;             // 524288 floats
    float* partial         = wmat + BATCH * CH * CH;          // 32 floats
    unsigned short* wmatb  = (unsigned short*)(partial + 64); // 524288 bf16

    pool_kernel<<<BATCH * CH, 256, 0, stream>>>(cond, pooled);
    wmat_kernel<<<CH * CH / 256, 256, 0, stream>>>(pooled, w_lin, b_lin, wmat, wmatb);
    conv_kernel<<<BATCH * 32, 256, 0, stream>>>(inp, wmatb, out);
    logdet_kernel<<<BATCH, 256, 0, stream>>>(wmat, wmatb, partial);
    finalize_kernel<<<1, 64, 0, stream>>>(partial, out + (size_t)BATCH * CH * HW);
}

// Round 8
// 81.844 us; speedup vs baseline: 1.0225x; 1.0225x over previous
//
#include <hip/hip_runtime.h>
#include <math.h>

#define BATCH 32
#define CH    128
#define HW    4096   // 64*64

typedef short short8 __attribute__((ext_vector_type(8)));   // 8 bf16 (4 VGPRs)
typedef float f32x4  __attribute__((ext_vector_type(4)));   // MFMA accumulator

#define SWZ(n) ((((n) >> 2) & 7) << 3)   // XOR swizzle of k-index by row

__device__ __forceinline__ unsigned short f2bf(float f) {   // RNE float->bf16
    unsigned int u = __float_as_uint(f);
    u = (u + 0x7FFF + ((u >> 16) & 1)) >> 16;
    return (unsigned short)u;
}
__device__ __forceinline__ float bf2f(unsigned short s) {
    return __uint_as_float(((unsigned int)s) << 16);
}
__device__ __forceinline__ float comp(const float4& v, int r) {  // static r after unroll
    return (r == 0) ? v.x : (r == 1) ? v.y : (r == 2) ? v.z : v.w;
}

// ---------------------------------------------------------------------------
// Kernel 1: pooled[b*C+c] = mean over HW of condition[b,c,:,:]
// ---------------------------------------------------------------------------
__global__ __launch_bounds__(256) void pool_kernel(const float* __restrict__ cond,
                                                   float* __restrict__ pooled) {
    int bc = blockIdx.x;
    const float4* base = (const float4*)(cond + (size_t)bc * HW);
    int tid = threadIdx.x;
    float s = 0.f;
#pragma unroll
    for (int k = 0; k < 4; ++k) {
        float4 v = base[tid + k * 256];
        s += v.x + v.y + v.z + v.w;
    }
    for (int off = 32; off; off >>= 1) s += __shfl_down(s, off, 64);
    __shared__ float red[4];
    if ((tid & 63) == 0) red[tid >> 6] = s;
    __syncthreads();
    if (tid == 0) pooled[bc] = (red[0] + red[1] + red[2] + red[3]) * (1.0f / HW);
}

// ---------------------------------------------------------------------------
// Kernel 2: wmat[b][o][i] = dot(pooled[b], w_lin[o*C+i]) + b_lin + (o==i)
// fp32 copy for logdet diagonal + bf16 copy for both MFMA consumers.
// ---------------------------------------------------------------------------
__global__ __launch_bounds__(256) void wmat_kernel(const float* __restrict__ pooled,
                                                   const float* __restrict__ w_lin,
                                                   const float* __restrict__ b_lin,
                                                   float* __restrict__ wmat,
                                                   unsigned short* __restrict__ wmatb) {
    __shared__ float4 pl[BATCH * CH / 4];   // pooled staged: pl[b*32 + k4]
    int tid = threadIdx.x;
    const float4* p4 = (const float4*)pooled;
    for (int idx = tid; idx < BATCH * CH / 4; idx += 256) pl[idx] = p4[idx];
    __syncthreads();

    int n = blockIdx.x * 256 + tid;
    const float4* row = (const float4*)(w_lin + (size_t)n * CH);
    float bl = b_lin[n];
    float acc[BATCH];
#pragma unroll
    for (int b = 0; b < BATCH; ++b) acc[b] = bl;

    for (int k4 = 0; k4 < CH / 4; ++k4) {
        float4 wv = row[k4];
#pragma unroll
        for (int b = 0; b < BATCH; ++b) {
            float4 pv = pl[b * 32 + k4];
            acc[b] += pv.x * wv.x + pv.y * wv.y + pv.z * wv.z + pv.w * wv.w;
        }
    }
    int o = n >> 7, i = n & 127;
    float diag = (o == i) ? 1.0f : 0.0f;
#pragma unroll
    for (int b = 0; b < BATCH; ++b) {
        float v = acc[b] + diag;
        wmat [(size_t)b * (CH * CH) + n] = v;
        wmatb[(size_t)b * (CH * CH) + n] = f2bf(v);
    }
}

// ---------------------------------------------------------------------------
// Kernel 3 (fused):
//   blocks 0..31: per-sample log|det W| via MFMA series (validated r4-r6).
//   blocks 32..1055: MFMA conv, K-STRIP PIPELINED: K staged in 4 strips of
//     32; strip g+1 global loads issued before the barrier and kept in
//     flight across it (raw s_barrier + lgkmcnt-only wait -- avoids hipcc's
//     vmcnt(0) drain at __syncthreads) while MFMA consumes strip g.
//     Single LDS buffer is race-free: per-strip write/read address sets are
//     identical and disjoint across strips (XOR swizzle bijective per strip).
// ---------------------------------------------------------------------------
__global__ __launch_bounds__(256, 4) void fused_kernel(const float* __restrict__ inp,
                                                       const float* __restrict__ wmat,
                                                       const unsigned short* __restrict__ wmatb,
                                                       float* __restrict__ out,
                                                       float* __restrict__ partial) {
    __shared__ __align__(16) short X[CH * 136];   // bf16 [row][k^swz], 34816 B
    int tid  = threadIdx.x;
    int lane = tid & 63;
    int ln   = lane & 15;                // row/col within 16
    int lg   = lane >> 4;                // k-group 0..3
    int och0 = (tid >> 6) * 32;          // wave's m-base

    if (blockIdx.x < BATCH) {
        // ---------------- logdet (MFMA series, unchanged) ----------------
        int b = blockIdx.x;
        const float*          Wb = wmat  + (size_t)b * CH * CH;
        const unsigned short* wb = wmatb + (size_t)b * CH * CH;

        // ---- stage ÊT[n][k^swz] = Ê[k][n], diag zeroed
        {
            int q  = tid & 31;           // col-quad: n = 4q..4q+3
            int ks = tid >> 5;           // 0..7
            const float* sb = Wb + 4 * q;
#pragma unroll
            for (int m = 0; m < 4; ++m) {
                int k0 = m * 32 + ks * 4;
                float4 r0 = *(const float4*)(sb + (size_t)(k0 + 0) * CH);
                float4 r1 = *(const float4*)(sb + (size_t)(k0 + 1) * CH);
                float4 r2 = *(const float4*)(sb + (size_t)(k0 + 2) * CH);
                float4 r3 = *(const float4*)(sb + (size_t)(k0 + 3) * CH);
#pragma unroll
                for (int r = 0; r < 4; ++r) {
                    int n = 4 * q + r;
                    float a0 = comp(r0, r), a1 = comp(r1, r);
                    float a2 = comp(r2, r), a3 = comp(r3, r);
                    if (k0 + 0 == n) a0 = 0.f;
                    if (k0 + 1 == n) a1 = 0.f;
                    if (k0 + 2 == n) a2 = 0.f;
                    if (k0 + 3 == n) a3 = 0.f;
                    ushort4 v;
                    v.x = f2bf(a0); v.y = f2bf(a1); v.z = f2bf(a2); v.w = f2bf(a3);
                    *(ushort4*)&X[n * 136 + (k0 ^ SWZ(n))] = v;
                }
            }
        }

        // ---- A fragments: Ê rows from wmatb, diag slot zeroed
        short8 afr[2][4];
#pragma unroll
        for (int mt = 0; mt < 2; ++mt) {
            int row = och0 + mt * 16 + ln;
#pragma unroll
            for (int g = 0; g < 4; ++g) {
                short8 v = *(const short8*)&wb[(size_t)row * CH + g * 32 + lg * 8];
#pragma unroll
                for (int j = 0; j < 8; ++j)
                    if (g * 32 + lg * 8 + j == row) v[j] = 0;
                afr[mt][g] = v;
            }
        }
        __syncthreads();

        // ---- D = Ê² via MFMA
        f32x4 acc[2][8];
#pragma unroll
        for (int mt = 0; mt < 2; ++mt)
#pragma unroll
            for (int nt = 0; nt < 8; ++nt) acc[mt][nt] = (f32x4){0.f, 0.f, 0.f, 0.f};
#pragma unroll
        for (int g = 0; g < 4; ++g) {
#pragma unroll
            for (int nt = 0; nt < 8; ++nt) {
                int n = nt * 16 + ln;
                short8 bfr = *(const short8*)&X[n * 136 + ((g * 32 + lg * 8) ^ SWZ(n))];
                acc[0][nt] = __builtin_amdgcn_mfma_f32_16x16x32_bf16(afr[0][g], bfr, acc[0][nt], 0, 0, 0);
                acc[1][nt] = __builtin_amdgcn_mfma_f32_16x16x32_bf16(afr[1][g], bfr, acc[1][nt], 0, 0, 0);
            }
        }

        // ---- traces: t3 (ÊT still in LDS) + diagonal terms
        float ld = 0.f;
#pragma unroll
        for (int mt = 0; mt < 2; ++mt) {
#pragma unroll
            for (int nt = 0; nt < 8; ++nt) {
#pragma unroll
                for (int reg = 0; reg < 4; ++reg) {
                    int row = och0 + mt * 16 + lg * 4 + reg;
                    int col = nt * 16 + ln;
                    float v = acc[mt][nt][reg];
                    float eT = bf2f((unsigned short)X[row * 136 + (col ^ SWZ(row))]);
                    ld += v * eT * (1.f / 3.f);
                    if (row == col) {
                        float d = Wb[(size_t)row * CH + row] - 1.0f;
                        ld += logf(fabsf(1.f + d)) + v * d - 0.5f * v;
                    }
                }
            }
        }
        __syncthreads();

        // ---- write D (bf16) for the transpose needed by tr(Ê⁴)
#pragma unroll
        for (int mt = 0; mt < 2; ++mt)
#pragma unroll
            for (int nt = 0; nt < 8; ++nt)
#pragma unroll
                for (int reg = 0; reg < 4; ++reg) {
                    int row = och0 + mt * 16 + lg * 4 + reg;
                    int col = nt * 16 + ln;
                    X[row * 136 + (col ^ SWZ(row))] = (short)f2bf(acc[mt][nt][reg]);
                }
        __syncthreads();

        // ---- t4 = sum D[r][c]*D[c][r]
#pragma unroll
        for (int mt = 0; mt < 2; ++mt)
#pragma unroll
            for (int nt = 0; nt < 8; ++nt)
#pragma unroll
                for (int reg = 0; reg < 4; ++reg) {
                    int row = och0 + mt * 16 + lg * 4 + reg;
                    int col = nt * 16 + ln;
                    float dT = bf2f((unsigned short)X[col * 136 + (row ^ SWZ(col))]);
                    ld -= acc[mt][nt][reg] * dT * 0.25f;
                }

        for (int off = 32; off; off >>= 1) ld += __shfl_down(ld, off, 64);
        __syncthreads();
        float* red = (float*)X;
        if (lane == 0) red[tid >> 6] = ld;
        __syncthreads();
        if (tid == 0) partial[b] = red[0] + red[1] + red[2] + red[3];
    } else {
        // ---------------- MFMA conv, k-strip pipelined ----------------
        int cb   = blockIdx.x - BATCH;
        int b    = cb >> 5;                  // 0..31
        int tile = cb & 31;                  // 0..31
        int pix0 = tile * 128;

        int q  = tid & 31;                   // pixel-quad: pix = 4q..4q+3
        int ks = tid >> 5;                   // 0..7
        const float* sb = inp + (size_t)b * CH * HW + pix0 + 4 * q;

        // ---- prologue: issue strip-0 loads (k rows ks*4 .. ks*4+3)
        float4 stg[4];
#pragma unroll
        for (int r = 0; r < 4; ++r)
            stg[r] = *(const float4*)(sb + (size_t)(ks * 4 + r) * HW);

        // ---- A fragments (W bf16 rows, L2-hot) while strip-0 is in flight
        const unsigned short* wb = wmatb + (size_t)b * CH * CH;
        short8 afr[2][4];
#pragma unroll
        for (int mt = 0; mt < 2; ++mt)
#pragma unroll
            for (int g = 0; g < 4; ++g)
                afr[mt][g] = *(const short8*)&wb[(size_t)(och0 + mt * 16 + ln) * CH + g * 32 + lg * 8];

        f32x4 acc[2][8];
#pragma unroll
        for (int mt = 0; mt < 2; ++mt)
#pragma unroll
            for (int nt = 0; nt < 8; ++nt) acc[mt][nt] = (f32x4){0.f, 0.f, 0.f, 0.f};

#pragma unroll
        for (int g = 0; g < 4; ++g) {
            // ---- convert strip g -> bf16 LDS [pix][k^swz] (4x4 transpose)
            int k0 = g * 32 + ks * 4;
#pragma unroll
            for (int r = 0; r < 4; ++r) {
                int pix = 4 * q + r;
                ushort4 v;
                v.x = f2bf(comp(stg[0], r));
                v.y = f2bf(comp(stg[1], r));
                v.z = f2bf(comp(stg[2], r));
                v.w = f2bf(comp(stg[3], r));
                *(ushort4*)&X[pix * 136 + (k0 ^ SWZ(pix))] = v;
            }
            // ---- issue strip g+1 loads; stay in flight across the barrier
            if (g < 3) {
#pragma unroll
                for (int r = 0; r < 4; ++r)
                    stg[r] = *(const float4*)(sb + (size_t)((g + 1) * 32 + ks * 4 + r) * HW);
            }
            // LDS-write visibility only; do NOT drain vmcnt (in-flight loads)
            asm volatile("s_waitcnt lgkmcnt(0)" ::: "memory");
            __builtin_amdgcn_s_barrier();
            __builtin_amdgcn_sched_barrier(0);

            // ---- MFMA strip g: 8 nt x 2 mt
#pragma unroll
            for (int nt = 0; nt < 8; ++nt) {
                int pix = nt * 16 + ln;
                short8 bfr = *(const short8*)&X[pix * 136 + ((g * 32 + lg * 8) ^ SWZ(pix))];
                acc[0][nt] = __builtin_amdgcn_mfma_f32_16x16x32_bf16(bfr, afr[0][g], acc[0][nt], 0, 0, 0);
                acc[1][nt] = __builtin_amdgcn_mfma_f32_16x16x32_bf16(bfr, afr[1][g], acc[1][nt], 0, 0, 0);
            }
        }

        // ---- store: D col=ln(och), row=lg*4+reg(pix) -> float4 over pix
        float* ob = out + (size_t)b * CH * HW + pix0;
#pragma unroll
        for (int mt = 0; mt < 2; ++mt) {
            int och = och0 + mt * 16 + ln;
#pragma unroll
            for (int nt = 0; nt < 8; ++nt) {
                int px = nt * 16 + lg * 4;
                float4 v = make_float4(acc[mt][nt][0], acc[mt][nt][1],
                                       acc[mt][nt][2], acc[mt][nt][3]);
                *(float4*)(ob + (size_t)och * HW + px) = v;
            }
        }
    }
}

// ---------------------------------------------------------------------------
// Kernel 4: log_det = HW * mean_b(partial[b]) = sum * 128
// ---------------------------------------------------------------------------
__global__ void finalize_kernel(const float* __restrict__ partial,
                                float* __restrict__ out_scalar) {
    int tid = threadIdx.x;
    float v = (tid < BATCH) ? partial[tid] : 0.f;
    for (int off = 32; off; off >>= 1) v += __shfl_down(v, off, 64);
    if (tid == 0) out_scalar[0] = v * 128.0f;
}

// ---------------------------------------------------------------------------
extern "C" void kernel_launch(void* const* d_in, const int* in_sizes, int n_in,
                              void* d_out, int out_size, void* d_ws, size_t ws_size,
                              hipStream_t stream) {
    const float* inp   = (const float*)d_in[0];
    const float* cond  = (const float*)d_in[1];
    const float* w_lin = (const float*)d_in[2];
    const float* b_lin = (const float*)d_in[3];
    float* out = (float*)d_out;

    float* pooled          = (float*)d_ws;                    // 4096 floats
    float* wmat            = pooled + BATCH * CH;             // 524288 floats
    float* partial         = wmat + BATCH * CH * CH;          // 32 floats
    unsigned short* wmatb  = (unsigned short*)(partial + 64); // 524288 bf16

    pool_kernel<<<BATCH * CH, 256, 0, stream>>>(cond, pooled);
    wmat_kernel<<<CH * CH / 256, 256, 0, stream>>>(pooled, w_lin, b_lin, wmat, wmatb);
    fused_kernel<<<BATCH + BATCH * 32, 256, 0, stream>>>(inp, wmat, wmatb, out, partial);
    finalize_kernel<<<1, 64, 0, stream>>>(partial, out + (size_t)BATCH * CH * HW);
}

// Round 10
// 77.749 us; speedup vs baseline: 1.0764x; 1.0527x over previous
//
#include <hip/hip_runtime.h>
#include <math.h>

#define BATCH 32
#define CH    128
#define HW    4096   // 64*64

typedef short short8 __attribute__((ext_vector_type(8)));   // 8 bf16 (4 VGPRs)
typedef float f32x4  __attribute__((ext_vector_type(4)));   // MFMA accumulator

#define SWZ(n) ((((n) >> 2) & 7) << 3)   // XOR swizzle of k-index by row

__device__ __forceinline__ unsigned short f2bf(float f) {   // RNE float->bf16
    unsigned int u = __float_as_uint(f);
    u = (u + 0x7FFF + ((u >> 16) & 1)) >> 16;
    return (unsigned short)u;
}
__device__ __forceinline__ float bf2f(unsigned short s) {
    return __uint_as_float(((unsigned int)s) << 16);
}
__device__ __forceinline__ float comp(const float4& v, int r) {  // static r after unroll
    return (r == 0) ? v.x : (r == 1) ? v.y : (r == 2) ? v.z : v.w;
}

// ---------------------------------------------------------------------------
// Kernel 1: pooled[b*C+c] = mean over HW of condition[b,c,:,:]
// ---------------------------------------------------------------------------
__global__ __launch_bounds__(256) void pool_kernel(const float* __restrict__ cond,
                                                   float* __restrict__ pooled) {
    int bc = blockIdx.x;
    const float4* base = (const float4*)(cond + (size_t)bc * HW);
    int tid = threadIdx.x;
    float s = 0.f;
#pragma unroll
    for (int k = 0; k < 4; ++k) {
        float4 v = base[tid + k * 256];
        s += v.x + v.y + v.z + v.w;
    }
    for (int off = 32; off; off >>= 1) s += __shfl_down(s, off, 64);
    __shared__ float red[4];
    if ((tid & 63) == 0) red[tid >> 6] = s;
    __syncthreads();
    if (tid == 0) pooled[bc] = (red[0] + red[1] + red[2] + red[3]) * (1.0f / HW);
}

// ---------------------------------------------------------------------------
// Kernel 2: wmat[b][o][i] = dot(pooled[b], w_lin[o*C+i]) + b_lin + (o==i)
// fp32 copy for logdet diagonal + bf16 copy for both MFMA consumers.
// Block 0 also zeroes the logdet completion counter for this launch.
// ---------------------------------------------------------------------------
__global__ __launch_bounds__(256) void wmat_kernel(const float* __restrict__ pooled,
                                                   const float* __restrict__ w_lin,
                                                   const float* __restrict__ b_lin,
                                                   float* __restrict__ wmat,
                                                   unsigned short* __restrict__ wmatb,
                                                   unsigned* __restrict__ counter) {
    if (blockIdx.x == 0 && threadIdx.x == 0) *counter = 0u;

    __shared__ float4 pl[BATCH * CH / 4];   // pooled staged: pl[b*32 + k4]
    int tid = threadIdx.x;
    const float4* p4 = (const float4*)pooled;
    for (int idx = tid; idx < BATCH * CH / 4; idx += 256) pl[idx] = p4[idx];
    __syncthreads();

    int n = blockIdx.x * 256 + tid;
    const float4* row = (const float4*)(w_lin + (size_t)n * CH);
    float bl = b_lin[n];
    float acc[BATCH];
#pragma unroll
    for (int b = 0; b < BATCH; ++b) acc[b] = bl;

    for (int k4 = 0; k4 < CH / 4; ++k4) {
        float4 wv = row[k4];
#pragma unroll
        for (int b = 0; b < BATCH; ++b) {
            float4 pv = pl[b * 32 + k4];
            acc[b] += pv.x * wv.x + pv.y * wv.y + pv.z * wv.z + pv.w * wv.w;
        }
    }
    int o = n >> 7, i = n & 127;
    float diag = (o == i) ? 1.0f : 0.0f;
#pragma unroll
    for (int b = 0; b < BATCH; ++b) {
        float v = acc[b] + diag;
        wmat [(size_t)b * (CH * CH) + n] = v;
        wmatb[(size_t)b * (CH * CH) + n] = f2bf(v);
    }
}

// ---------------------------------------------------------------------------
// Kernel 3 (fused):
//   blocks 0..31: per-sample log|det W| via MFMA series (validated r4/r5).
//     Last finishing block sums the 32 partials IN ORDER (deterministic)
//     and writes the output scalar -- no separate finalize launch.
//   blocks 32..1055: MFMA conv (r6 core, validated):
//     - XCD-bijective block swizzle: each XCD owns 4 consecutive b
//       (W + inp tiles L2-local per XCD).
//     - nontemporal f32x4 stores: out is write-once; skip write-allocate
//       so L2/L3 stay dedicated to the inp/cond read streams.
// ---------------------------------------------------------------------------
__global__ __launch_bounds__(256, 4) void fused_kernel(const float* __restrict__ inp,
                                                       const float* __restrict__ wmat,
                                                       const unsigned short* __restrict__ wmatb,
                                                       float* __restrict__ out,
                                                       float* __restrict__ partial,
                                                       unsigned* __restrict__ counter,
                                                       float* __restrict__ out_scalar) {
    __shared__ __align__(16) short X[CH * 136];   // bf16 [row][k^swz], 34816 B
    int tid  = threadIdx.x;
    int lane = tid & 63;
    int ln   = lane & 15;                // row/col within 16
    int lg   = lane >> 4;                // k-group 0..3
    int och0 = (tid >> 6) * 32;          // wave's m-base

    if (blockIdx.x < BATCH) {
        // ---------------- logdet (MFMA series) ----------------
        int b = blockIdx.x;
        const float*          Wb = wmat  + (size_t)b * CH * CH;
        const unsigned short* wb = wmatb + (size_t)b * CH * CH;

        // ---- stage ÊT[n][k^swz] = Ê[k][n], diag zeroed (transpose of W rows)
        {
            int q  = tid & 31;           // col-quad: n = 4q..4q+3
            int ks = tid >> 5;           // 0..7
            const float* sb = Wb + 4 * q;
#pragma unroll
            for (int m = 0; m < 4; ++m) {
                int k0 = m * 32 + ks * 4;
                float4 r0 = *(const float4*)(sb + (size_t)(k0 + 0) * CH);
                float4 r1 = *(const float4*)(sb + (size_t)(k0 + 1) * CH);
                float4 r2 = *(const float4*)(sb + (size_t)(k0 + 2) * CH);
                float4 r3 = *(const float4*)(sb + (size_t)(k0 + 3) * CH);
#pragma unroll
                for (int r = 0; r < 4; ++r) {
                    int n = 4 * q + r;
                    float a0 = comp(r0, r), a1 = comp(r1, r);
                    float a2 = comp(r2, r), a3 = comp(r3, r);
                    if (k0 + 0 == n) a0 = 0.f;
                    if (k0 + 1 == n) a1 = 0.f;
                    if (k0 + 2 == n) a2 = 0.f;
                    if (k0 + 3 == n) a3 = 0.f;
                    ushort4 v;
                    v.x = f2bf(a0); v.y = f2bf(a1); v.z = f2bf(a2); v.w = f2bf(a3);
                    *(ushort4*)&X[n * 136 + (k0 ^ SWZ(n))] = v;
                }
            }
        }

        // ---- A fragments: Ê rows from wmatb, diag slot zeroed
        short8 afr[2][4];
#pragma unroll
        for (int mt = 0; mt < 2; ++mt) {
            int row = och0 + mt * 16 + ln;
#pragma unroll
            for (int g = 0; g < 4; ++g) {
                short8 v = *(const short8*)&wb[(size_t)row * CH + g * 32 + lg * 8];
#pragma unroll
                for (int j = 0; j < 8; ++j)
                    if (g * 32 + lg * 8 + j == row) v[j] = 0;
                afr[mt][g] = v;
            }
        }
        __syncthreads();

        // ---- D = Ê² via MFMA
        f32x4 acc[2][8];
#pragma unroll
        for (int mt = 0; mt < 2; ++mt)
#pragma unroll
            for (int nt = 0; nt < 8; ++nt) acc[mt][nt] = (f32x4){0.f, 0.f, 0.f, 0.f};
#pragma unroll
        for (int g = 0; g < 4; ++g) {
#pragma unroll
            for (int nt = 0; nt < 8; ++nt) {
                int n = nt * 16 + ln;
                short8 bfr = *(const short8*)&X[n * 136 + ((g * 32 + lg * 8) ^ SWZ(n))];
                acc[0][nt] = __builtin_amdgcn_mfma_f32_16x16x32_bf16(afr[0][g], bfr, acc[0][nt], 0, 0, 0);
                acc[1][nt] = __builtin_amdgcn_mfma_f32_16x16x32_bf16(afr[1][g], bfr, acc[1][nt], 0, 0, 0);
            }
        }

        // ---- traces: t3 (ÊT still in LDS) + diagonal terms
        float ld = 0.f;
#pragma unroll
        for (int mt = 0; mt < 2; ++mt) {
#pragma unroll
            for (int nt = 0; nt < 8; ++nt) {
#pragma unroll
                for (int reg = 0; reg < 4; ++reg) {
                    int row = och0 + mt * 16 + lg * 4 + reg;
                    int col = nt * 16 + ln;
                    float v = acc[mt][nt][reg];
                    float eT = bf2f((unsigned short)X[row * 136 + (col ^ SWZ(row))]);
                    ld += v * eT * (1.f / 3.f);
                    if (row == col) {
                        float d = Wb[(size_t)row * CH + row] - 1.0f;
                        ld += logf(fabsf(1.f + d)) + v * d - 0.5f * v;
                    }
                }
            }
        }
        __syncthreads();   // all ÊT reads done -> reuse LDS for D

        // ---- write D (bf16) for the transpose needed by tr(Ê⁴)
#pragma unroll
        for (int mt = 0; mt < 2; ++mt)
#pragma unroll
            for (int nt = 0; nt < 8; ++nt)
#pragma unroll
                for (int reg = 0; reg < 4; ++reg) {
                    int row = och0 + mt * 16 + lg * 4 + reg;
                    int col = nt * 16 + ln;
                    X[row * 136 + (col ^ SWZ(row))] = (short)f2bf(acc[mt][nt][reg]);
                }
        __syncthreads();

        // ---- t4 = sum D[r][c]*D[c][r]
#pragma unroll
        for (int mt = 0; mt < 2; ++mt)
#pragma unroll
            for (int nt = 0; nt < 8; ++nt)
#pragma unroll
                for (int reg = 0; reg < 4; ++reg) {
                    int row = och0 + mt * 16 + lg * 4 + reg;
                    int col = nt * 16 + ln;
                    float dT = bf2f((unsigned short)X[col * 136 + (row ^ SWZ(col))]);
                    ld -= acc[mt][nt][reg] * dT * 0.25f;
                }

        for (int off = 32; off; off >>= 1) ld += __shfl_down(ld, off, 64);
        __syncthreads();
        float* red = (float*)X;
        if (lane == 0) red[tid >> 6] = ld;
        __syncthreads();

        // ---- publish partial; last block (deterministic order) writes scalar
        if (tid == 0) {
            float my = red[0] + red[1] + red[2] + red[3];
            __hip_atomic_store(&partial[b], my, __ATOMIC_RELAXED,
                               __HIP_MEMORY_SCOPE_AGENT);
            __threadfence();
            unsigned prev = __hip_atomic_fetch_add(counter, 1u, __ATOMIC_ACQ_REL,
                                                   __HIP_MEMORY_SCOPE_AGENT);
            if (prev == BATCH - 1) {
                __threadfence();
                float s = 0.f;
#pragma unroll
                for (int i = 0; i < BATCH; ++i)
                    s += __hip_atomic_load(&partial[i], __ATOMIC_RELAXED,
                                           __HIP_MEMORY_SCOPE_AGENT);
                out_scalar[0] = s * 128.0f;
            }
        }
    } else {
        // ---------------- MFMA conv (r6 core + swizzle + NT stores) --------
        int cb = blockIdx.x - BATCH;
        cb = (cb & 7) * 128 + (cb >> 3);     // bijective XCD swizzle (1024 = 8*128)
        int b    = cb >> 5;                  // 0..31
        int tile = cb & 31;                  // 0..31
        int pix0 = tile * 128;

        int q  = tid & 31;                   // pixel-quad: pix = 4q..4q+3
        int ks = tid >> 5;                   // 0..7
        const float* sb = inp + (size_t)b * CH * HW + pix0 + 4 * q;

        // ---- issue all 16 X loads in two 8-reg batches
        float4 s0[8], s1[8];
#pragma unroll
        for (int m = 0; m < 2; ++m)
#pragma unroll
            for (int r = 0; r < 4; ++r)
                s0[m * 4 + r] = *(const float4*)(sb + (size_t)(m * 32 + ks * 4 + r) * HW);
#pragma unroll
        for (int m = 0; m < 2; ++m)
#pragma unroll
            for (int r = 0; r < 4; ++r)
                s1[m * 4 + r] = *(const float4*)(sb + (size_t)((m + 2) * 32 + ks * 4 + r) * HW);

        // ---- A fragments (W bf16 rows, XCD-L2-hot) while X loads in flight
        const unsigned short* wb = wmatb + (size_t)b * CH * CH;
        short8 afr[2][4];
#pragma unroll
        for (int mt = 0; mt < 2; ++mt)
#pragma unroll
            for (int g = 0; g < 4; ++g)
                afr[mt][g] = *(const short8*)&wb[(size_t)(och0 + mt * 16 + ln) * CH + g * 32 + lg * 8];

        // ---- convert -> bf16 LDS [pix][k^swz] (in-thread 4x4 transpose)
#pragma unroll
        for (int m = 0; m < 2; ++m) {
            int k0 = m * 32 + ks * 4;
#pragma unroll
            for (int r = 0; r < 4; ++r) {
                int pix = 4 * q + r;
                ushort4 v;
                v.x = f2bf(comp(s0[m * 4 + 0], r));
                v.y = f2bf(comp(s0[m * 4 + 1], r));
                v.z = f2bf(comp(s0[m * 4 + 2], r));
                v.w = f2bf(comp(s0[m * 4 + 3], r));
                *(ushort4*)&X[pix * 136 + (k0 ^ SWZ(pix))] = v;
            }
        }
#pragma unroll
        for (int m = 0; m < 2; ++m) {
            int k0 = (m + 2) * 32 + ks * 4;
#pragma unroll
            for (int r = 0; r < 4; ++r) {
                int pix = 4 * q + r;
                ushort4 v;
                v.x = f2bf(comp(s1[m * 4 + 0], r));
                v.y = f2bf(comp(s1[m * 4 + 1], r));
                v.z = f2bf(comp(s1[m * 4 + 2], r));
                v.w = f2bf(comp(s1[m * 4 + 3], r));
                *(ushort4*)&X[pix * 136 + (k0 ^ SWZ(pix))] = v;
            }
        }
        __syncthreads();

        // ---- MFMA: acc[mt][nt] = D[pix-tile nt][och-tile mt]
        f32x4 acc[2][8];
#pragma unroll
        for (int mt = 0; mt < 2; ++mt)
#pragma unroll
            for (int nt = 0; nt < 8; ++nt) acc[mt][nt] = (f32x4){0.f, 0.f, 0.f, 0.f};

#pragma unroll
        for (int g = 0; g < 4; ++g) {
#pragma unroll
            for (int nt = 0; nt < 8; ++nt) {
                int pix = nt * 16 + ln;
                short8 bfr = *(const short8*)&X[pix * 136 + ((g * 32 + lg * 8) ^ SWZ(pix))];
                acc[0][nt] = __builtin_amdgcn_mfma_f32_16x16x32_bf16(bfr, afr[0][g], acc[0][nt], 0, 0, 0);
                acc[1][nt] = __builtin_amdgcn_mfma_f32_16x16x32_bf16(bfr, afr[1][g], acc[1][nt], 0, 0, 0);
            }
        }

        // ---- nontemporal f32x4 stores (write-once stream, no L2 allocate)
        float* ob = out + (size_t)b * CH * HW + pix0;
#pragma unroll
        for (int mt = 0; mt < 2; ++mt) {
            int och = och0 + mt * 16 + ln;
#pragma unroll
            for (int nt = 0; nt < 8; ++nt) {
                int px = nt * 16 + lg * 4;
                __builtin_nontemporal_store(acc[mt][nt],
                                            (f32x4*)(ob + (size_t)och * HW + px));
            }
        }
    }
}

// ---------------------------------------------------------------------------
extern "C" void kernel_launch(void* const* d_in, const int* in_sizes, int n_in,
                              void* d_out, int out_size, void* d_ws, size_t ws_size,
                              hipStream_t stream) {
    const float* inp   = (const float*)d_in[0];
    const float* cond  = (const float*)d_in[1];
    const float* w_lin = (const float*)d_in[2];
    const float* b_lin = (const float*)d_in[3];
    float* out = (float*)d_out;

    float* pooled          = (float*)d_ws;                    // 4096 floats
    float* wmat            = pooled + BATCH * CH;             // 524288 floats
    float* partial         = wmat + BATCH * CH * CH;          // 32 floats
    unsigned* counter      = (unsigned*)(partial + 32);       // 1 uint
    unsigned short* wmatb  = (unsigned short*)(partial + 64); // 524288 bf16

    pool_kernel<<<BATCH * CH, 256, 0, stream>>>(cond, pooled);
    wmat_kernel<<<CH * CH / 256, 256, 0, stream>>>(pooled, w_lin, b_lin, wmat, wmatb, counter);
    fused_kernel<<<BATCH + BATCH * 32, 256, 0, stream>>>(inp, wmat, wmatb, out, partial,
                                                         counter, out + (size_t)BATCH * CH * HW);
}